// Round 14
// baseline (3856.716 us; speedup 1.0000x reference)
//
#include <hip/hip_runtime.h>
#include <hip/hip_bf16.h>

typedef __hip_bfloat16 bf16;
typedef __attribute__((ext_vector_type(8))) short s16x8;   // 8 bf16 (MFMA A/B frag)
typedef __attribute__((ext_vector_type(4))) float f32x4;   // MFMA C/D frag
typedef __attribute__((ext_vector_type(4))) int   i32x4;

#define BATCH   64
#define SEQ     256
#define HID     1024
#define GATES   4096
#define NWG     256
#define THREADS 256
#define UNITS   8
#define NCOLS   32
#define ROWSTRIDE 2056       // 2048 K + 8 pad elems
#define BH      (BATCH * HID)

// ---- ws layout: flags first (4 KB), h storage after ----
// HIST path: h0[t]/h1[t] each get a UNIQUE slot (write-once addresses -> plain
// cached reads can never be stale; no fences, no ring-protect; L0 free-runs).
// RING fallback (ws too small): 8/2-slot rings with sc0 sc1 bypass reads.
#define HBASE_OFF  4096ull
#define WS_NEED    (HBASE_OFF + 2ull * SEQ * BH * 2)   // 67,112,960 B
#define H0_RS 8
#define H1_RS 2

#define OUT_HN  ((size_t)BATCH * SEQ * HID)
#define OUT_CN  (OUT_HN + 2ull * BATCH * HID)

__device__ __forceinline__ short f2bf(float f) {   // rne fp32->bf16
    unsigned int u = __builtin_bit_cast(unsigned int, f);
    u = (u + 0x7fffu + ((u >> 16) & 1u)) >> 16;
    return (short)u;
}

// ---- monolithic h GEMM over K=1024 (single base + immediate offsets,
// counted-vmcnt pipeline, sched_barrier rule #18) ----
#define GLD(i, OFF, CF) asm volatile("global_load_dwordx4 %0, %1, off offset:" OFF " " CF \
                                     : "=v"(h[i]) : "v"(xrow));
#define MM8(B0) \
    _Pragma("unroll") \
    for (int kk = (B0); kk < (B0) + 8; ++kk) { \
        s16x8 b0 = *(const s16x8*)(s0 + kk * 32); \
        s16x8 b1 = *(const s16x8*)(s1 + kk * 32); \
        s16x8 av = __builtin_bit_cast(s16x8, h[kk]); \
        a0 = __builtin_amdgcn_mfma_f32_16x16x32_bf16(av, b0, a0, 0, 0, 0); \
        a1 = __builtin_amdgcn_mfma_f32_16x16x32_bf16(av, b1, a1, 0, 0, 0); \
    }
#define GEMM_FN(NAME, CF) \
__device__ __forceinline__ void NAME(const bf16* xrow, const bf16* s0, const bf16* s1, \
                                     f32x4& a0, f32x4& a1) \
{ \
    i32x4 h[32]; \
    GLD(0,"0",CF)    GLD(1,"64",CF)   GLD(2,"128",CF)  GLD(3,"192",CF) \
    GLD(4,"256",CF)  GLD(5,"320",CF)  GLD(6,"384",CF)  GLD(7,"448",CF) \
    GLD(8,"512",CF)  GLD(9,"576",CF)  GLD(10,"640",CF) GLD(11,"704",CF) \
    GLD(12,"768",CF) GLD(13,"832",CF) GLD(14,"896",CF) GLD(15,"960",CF) \
    GLD(16,"1024",CF) GLD(17,"1088",CF) GLD(18,"1152",CF) GLD(19,"1216",CF) \
    GLD(20,"1280",CF) GLD(21,"1344",CF) GLD(22,"1408",CF) GLD(23,"1472",CF) \
    asm volatile("s_waitcnt vmcnt(16)"); __builtin_amdgcn_sched_barrier(0); \
    MM8(0) \
    GLD(24,"1536",CF) GLD(25,"1600",CF) GLD(26,"1664",CF) GLD(27,"1728",CF) \
    GLD(28,"1792",CF) GLD(29,"1856",CF) GLD(30,"1920",CF) GLD(31,"1984",CF) \
    asm volatile("s_waitcnt vmcnt(16)"); __builtin_amdgcn_sched_barrier(0); \
    MM8(8) \
    asm volatile("s_waitcnt vmcnt(8)");  __builtin_amdgcn_sched_barrier(0); \
    MM8(16) \
    asm volatile("s_waitcnt vmcnt(0)");  __builtin_amdgcn_sched_barrier(0); \
    MM8(24) \
}
GEMM_FN(gemm_bt, "sc0 sc1")
GEMM_FN(gemm_p,  "")

// Embedding x-GEMM: plain cached fp32 loads.
__device__ __forceinline__ void gemm_f32c(const float* xrow, const bf16* s0, const bf16* s1,
                                          f32x4& a0, f32x4& a1)
{
#pragma unroll
    for (int c = 0; c < 4; ++c) {
        f32x4 xv[16];
#pragma unroll
        for (int i = 0; i < 8; ++i) {
            const float* p = xrow + (c * 8 + i) * 32;
            xv[2 * i]     = *(const f32x4*)p;
            xv[2 * i + 1] = *(const f32x4*)(p + 4);
        }
#pragma unroll
        for (int i = 0; i < 8; ++i) {
            const int kk = c * 8 + i;
            s16x8 af;
#pragma unroll
            for (int j = 0; j < 4; ++j) {
                af[j]     = f2bf(xv[2 * i][j]);
                af[4 + j] = f2bf(xv[2 * i + 1][j]);
            }
            s16x8 b0 = *(const s16x8*)(s0 + kk * 32);
            s16x8 b1 = *(const s16x8*)(s1 + kk * 32);
            a0 = __builtin_amdgcn_mfma_f32_16x16x32_bf16(af, b0, a0, 0, 0, 0);
            a1 = __builtin_amdgcn_mfma_f32_16x16x32_bf16(af, b1, a1, 0, 0, 0);
        }
    }
}

// Per-wave blocking poll of one 128-word flag chain with observed-min caching.
__device__ __forceinline__ void wave_poll(unsigned int* f, int tgt, int* seen) {
    if (tgt <= 0 || *seen >= tgt) return;
    const int l = threadIdx.x & 63;
    unsigned int* p0 = f + l;
    unsigned int* p1 = f + 64 + l;
    int a, b;
    for (;;) {
        a = (int)__hip_atomic_load(p0, __ATOMIC_RELAXED, __HIP_MEMORY_SCOPE_AGENT);
        b = (int)__hip_atomic_load(p1, __ATOMIC_RELAXED, __HIP_MEMORY_SCOPE_AGENT);
        if (__all((a >= tgt) && (b >= tgt))) break;
        __builtin_amdgcn_s_sleep(1);
    }
    int v = (a < b) ? a : b;
#pragma unroll
    for (int off = 32; off; off >>= 1) {
        int w = __shfl_xor(v, off, 64);
        v = (w < v) ? w : v;
    }
    *seen = v;
    asm volatile("" ::: "memory");
}

// One-shot non-blocking full-chain probe (fast path for the chunked GEMM).
__device__ __forceinline__ bool wave_probe(unsigned int* f, int tgt) {
    const int l = threadIdx.x & 63;
    int a = (int)__hip_atomic_load(f + l,      __ATOMIC_RELAXED, __HIP_MEMORY_SCOPE_AGENT);
    int b = (int)__hip_atomic_load(f + 64 + l, __ATOMIC_RELAXED, __HIP_MEMORY_SCOPE_AGENT);
    bool ok = __all((a >= tgt) && (b >= tgt));
    asm volatile("" ::: "memory");
    return ok;
}

// Blocking poll of ONE 16-WG group's flags (group g = chain words [16g,16g+16)).
__device__ __forceinline__ void gpoll(unsigned int* fch, int cg, int tgt) {
    unsigned int* p = fch + cg * 16 + (threadIdx.x & 15);
    for (;;) {
        int v = (int)__hip_atomic_load(p, __ATOMIC_RELAXED, __HIP_MEMORY_SCOPE_AGENT);
        if (__all(v >= tgt)) break;
        __builtin_amdgcn_s_sleep(1);
    }
    asm volatile("" ::: "memory");
}

// 4 cached 16B loads of one 128-unit chunk.
__device__ __forceinline__ void ld_chunk(const bf16* base, int cg, i32x4* hh) {
    const bf16* p = base + cg * 128;
    asm volatile("global_load_dwordx4 %0, %1, off"            : "=v"(hh[0]) : "v"(p));
    asm volatile("global_load_dwordx4 %0, %1, off offset:64"  : "=v"(hh[1]) : "v"(p));
    asm volatile("global_load_dwordx4 %0, %1, off offset:128" : "=v"(hh[2]) : "v"(p));
    asm volatile("global_load_dwordx4 %0, %1, off offset:192" : "=v"(hh[3]) : "v"(p));
}
__device__ __forceinline__ void mm_chunk(const i32x4* hh, const bf16* s0, const bf16* s1,
                                         int cg, f32x4& a0, f32x4& a1) {
#pragma unroll
    for (int j = 0; j < 4; ++j) {
        const int kk = cg * 4 + j;
        s16x8 b0 = *(const s16x8*)(s0 + kk * 32);
        s16x8 b1 = *(const s16x8*)(s1 + kk * 32);
        s16x8 av = __builtin_bit_cast(s16x8, hh[j]);
        a0 = __builtin_amdgcn_mfma_f32_16x16x32_bf16(av, b0, a0, 0, 0, 0);
        a1 = __builtin_amdgcn_mfma_f32_16x16x32_bf16(av, b1, a1, 0, 0, 0);
    }
}

// CHUNKED recurrence GEMM: units chunk g (= kk 4g..4g+3) is produced exactly by
// WGs 16g..16g+15 (this wave's rows by this wave of those WGs). Gate each chunk
// on ITS 16 producers only -> consumer starts on the first-ready group instead
// of max-of-128; polls pipeline with loads/MFMAs. Rotation grot staggers the
// starting group across consumer WGs. Fast path: full-chain probe -> monolithic.
__device__ __forceinline__ void gemm_chunk(const bf16* xrow, const bf16* s0, const bf16* s1,
                                           unsigned int* fch, int tgt, int grot,
                                           f32x4& a0, f32x4& a1)
{
    if (wave_probe(fch, tgt)) {                // all producers already done
        gemm_p(xrow, s0, s1, a0, a1);
        return;
    }
    i32x4 hA[4], hB[4];
    {
        const int c0 = grot & 7;
        gpoll(fch, c0, tgt);
        ld_chunk(xrow, c0, hA);
    }
#define STEP(i, CUR, NXT) \
    { \
        if ((i) < 7) { \
            const int cn = (grot + (i) + 1) & 7; \
            gpoll(fch, cn, tgt);               /* drains CUR's loads en route */ \
            ld_chunk(xrow, cn, NXT); \
            asm volatile("s_waitcnt vmcnt(4)"); \
        } else { \
            asm volatile("s_waitcnt vmcnt(0)"); \
        } \
        __builtin_amdgcn_sched_barrier(0); \
        mm_chunk(CUR, s0, s1, (grot + (i)) & 7, a0, a1); \
    }
    STEP(0, hA, hB) STEP(1, hB, hA) STEP(2, hA, hB) STEP(3, hB, hA)
    STEP(4, hA, hB) STEP(5, hB, hA) STEP(6, hA, hB) STEP(7, hB, hA)
#undef STEP
}

__global__ void ws_init(unsigned int* p, int n) {
    for (int i = blockIdx.x * blockDim.x + threadIdx.x; i < n; i += gridDim.x * blockDim.x)
        p[i] = 0u;
}

__global__ void __launch_bounds__(THREADS, 1)
lstm_enc(const int* __restrict__ src, const float* __restrict__ Wemb,
         const float* __restrict__ Wih, const float* __restrict__ Whh,
         const float* __restrict__ bih, const float* __restrict__ bhh,
         float* __restrict__ out, bf16* __restrict__ hbuf, int hist_on)
{
    __shared__ __align__(16) bf16 slab[NCOLS][ROWSTRIDE];   // 131,584 B
    __shared__ float bias[NCOLS];

    const int wg    = blockIdx.x;
    const int layer = wg >> 7;
    const int wgl   = wg & 127;
    const int j0    = wgl * UNITS;
    const int tid   = threadIdx.x;
    const int lane  = tid & 63;
    const int wave  = tid >> 6;
    const int m     = lane & 15;
    const int q     = lane >> 4;
    const int kq    = q * 8;
    const int b_a   = wave * 16 + m;           // batch row this lane loads for A
    const int grot  = wgl >> 4;                // chunk rotation (stagger groups)

    // ---- weight slab: rows = [i8|f8|g8|o8], K = [W_ih row | W_hh row] ----
    for (int r = 0; r < NCOLS; ++r) {
        int g = r >> 3, u = r & 7;
        size_t grow = (size_t)layer * GATES * HID + (size_t)(g * HID + j0 + u) * HID;
        int k = tid * 8;
        const float* s = (k < HID) ? (Wih + grow + k) : (Whh + grow + (k - HID));
        s16x8 v;
#pragma unroll
        for (int j = 0; j < 8; ++j) v[j] = f2bf(s[j]);
        *(s16x8*)&slab[r][k] = v;
    }
    if (tid < NCOLS) {
        int g = tid >> 3, u = tid & 7;
        int off = layer * GATES + g * HID + j0 + u;
        bias[tid] = bih[off] + bhh[off];
    }
    __syncthreads();                           // slab/bias ready (only barrier)

    unsigned int* flags = (unsigned int*)hbuf;                 // 2 x 512 words
    bf16* hb = (bf16*)((char*)hbuf + HBASE_OFF);
    bf16* h0 = hb;                             // HIST: [256][B][H]; RING: [8][B][H]
    bf16* h1 = hist_on ? hb + (size_t)SEQ * BH : hb + (size_t)H0_RS * BH;
    unsigned int* f0 = flags + wave * 128;             // this wave's L0 chain
    unsigned int* f1 = flags + 512 + wave * 128;       // this wave's L1 chain
    unsigned int* myflag = flags + layer * 512 + wave * 128 + wgl;

    const int u = m & 7;
    const float b_i = bias[u], b_f = bias[8 + u], b_g = bias[16 + u], b_o = bias[24 + u];
    float c_s[4] = {0.f, 0.f, 0.f, 0.f};
    int seenA = 0, seenB = 0;

    int sv = (layer == 0) ? src[b_a * SEQ] : 0;

    for (int t = 0; t < SEQ; ++t) {
        f32x4 acc0 = {0.f, 0.f, 0.f, 0.f};
        f32x4 acc1 = {0.f, 0.f, 0.f, 0.f};

        if (layer == 0) {
            // embedding x-GEMM: no cross-WG dep, overlaps producer spread
            const float* xF = Wemb + (size_t)sv * HID + kq;
            if (t + 1 < SEQ) sv = src[b_a * SEQ + t + 1];
            gemm_f32c(xF, &slab[m][kq], &slab[16 + m][kq], acc0, acc1);
            if (t >= 1) {
                if (hist_on)   // CHUNKED own-recurrence wait (group-gated)
                    gemm_chunk(h0 + (size_t)(t - 1) * BH + b_a * HID + kq,
                               &slab[m][HID + kq], &slab[16 + m][HID + kq],
                               f0, t, grot, acc0, acc1);
                else {
                    wave_poll(f0, t, &seenA);
                    gemm_bt(h0 + (size_t)((t - 1) & (H0_RS - 1)) * BH + b_a * HID + kq,
                            &slab[m][HID + kq], &slab[16 + m][HID + kq], acc0, acc1);
                }
            }
            if (!hist_on)                      // ring protect only needed on reuse
                wave_poll(f1, t - 7, &seenB);
        } else {
            wave_poll(f0, t + 1, &seenA);      // L0 ahead -> mostly cached/skipped
            if (hist_on) {
                gemm_p(h0 + (size_t)t * BH + b_a * HID + kq,
                       &slab[m][kq], &slab[16 + m][kq], acc0, acc1);
                if (t >= 1)    // CHUNKED own-recurrence wait (the critical one)
                    gemm_chunk(h1 + (size_t)(t - 1) * BH + b_a * HID + kq,
                               &slab[m][HID + kq], &slab[16 + m][HID + kq],
                               f1, t, grot, acc0, acc1);
            } else {
                gemm_bt(h0 + (size_t)(t & (H0_RS - 1)) * BH + b_a * HID + kq,
                        &slab[m][kq], &slab[16 + m][kq], acc0, acc1);
                wave_poll(f1, t, &seenB);
                if (t >= 1)
                    gemm_bt(h1 + (size_t)((t - 1) & (H1_RS - 1)) * BH + b_a * HID + kq,
                            &slab[m][HID + kq], &slab[16 + m][HID + kq], acc0, acc1);
            }
        }

        // in-wave epilogue: gate pairs sit in lane pair (u, u+8); same f32 math
        float hval[4];
#pragma unroll
        for (int r = 0; r < 4; ++r) {
            float p0 = __shfl_xor(acc0[r], 8, 64);
            float p1 = __shfl_xor(acc1[r], 8, 64);
            const bool lo = (m < 8);
            float gi = (lo ? acc0[r] : p0) + b_i;
            float gf = (lo ? p0 : acc0[r]) + b_f;
            float gg = (lo ? acc1[r] : p1) + b_g;
            float go = (lo ? p1 : acc1[r]) + b_o;
            float si = 1.f / (1.f + __expf(-gi));
            float sf = 1.f / (1.f + __expf(-gf));
            float so = 1.f / (1.f + __expf(-go));
            c_s[r] = sf * c_s[r] + si * tanhf(gg);
            hval[r] = so * tanhf(c_s[r]);
        }

        // h store (lanes m<8 own the unique copy), write-through to MALL.
        // HIST: slot t is a FRESH address (written exactly once, ever).
        bf16* hw = (layer == 0)
            ? h0 + (size_t)(hist_on ? t : (t & (H0_RS - 1))) * BH
            : h1 + (size_t)(hist_on ? t : (t & (H1_RS - 1))) * BH;
        if (m < 8) {
#pragma unroll
            for (int r = 0; r < 4; ++r) {
                int R = wave * 16 + q * 4 + r;
                __hip_atomic_store((unsigned short*)(hw + (size_t)R * HID + j0 + u),
                                   (unsigned short)f2bf(hval[r]),
                                   __ATOMIC_RELAXED, __HIP_MEMORY_SCOPE_AGENT);
            }
        }
        // per-wave drain + private flag post: no barrier, waves fully decoupled
        asm volatile("s_waitcnt vmcnt(0)"); __builtin_amdgcn_sched_barrier(0);
        asm volatile("" ::: "memory");
        if (lane == 0)
            __hip_atomic_store(myflag, (unsigned int)(t + 1),
                               __ATOMIC_RELAXED, __HIP_MEMORY_SCOPE_AGENT);

        // post-flag outputs: off the recurrence critical path
        if (layer == 1 && m < 8) {
#pragma unroll
            for (int r = 0; r < 4; ++r) {
                int R = wave * 16 + q * 4 + r;
                out[((size_t)R * SEQ + t) * HID + j0 + u] = hval[r];
            }
        }
        if (t == SEQ - 1 && m < 8) {
#pragma unroll
            for (int r = 0; r < 4; ++r) {
                int R = wave * 16 + q * 4 + r;
                size_t o = ((size_t)layer * BATCH + R) * HID + j0 + u;
                out[OUT_HN + o] = hval[r];
                out[OUT_CN + o] = c_s[r];
            }
        }
    }
}

extern "C" void kernel_launch(void* const* d_in, const int* in_sizes, int n_in,
                              void* d_out, int out_size, void* d_ws, size_t ws_size,
                              hipStream_t stream) {
    const int*   src  = (const int*)d_in[0];
    const float* emb  = (const float*)d_in[1];
    const float* W_ih = (const float*)d_in[2];
    const float* W_hh = (const float*)d_in[3];
    const float* b_ih = (const float*)d_in[4];
    const float* b_hh = (const float*)d_in[5];
    float* out  = (float*)d_out;
    bf16*  hbuf = (bf16*)d_ws;

    // zero the 1024 flag words at ws base (ws re-poisoned 0xAA each replay;
    // h slots need no init: each is written before it is ever read)
    ws_init<<<4, 256, 0, stream>>>((unsigned int*)d_ws, 1024);

    int hist_on = (ws_size >= (size_t)WS_NEED) ? 1 : 0;

    void* args[] = {&src, &emb, &W_ih, &W_hh, &b_ih, &b_hh, &out, &hbuf, &hist_on};
    hipLaunchCooperativeKernel((void*)lstm_enc, dim3(NWG), dim3(THREADS),
                               args, 0, stream);
}

// Round 15
// 3501.181 us; speedup vs baseline: 1.1015x; 1.1015x over previous
//
#include <hip/hip_runtime.h>
#include <hip/hip_bf16.h>

typedef __hip_bfloat16 bf16;
typedef __attribute__((ext_vector_type(8))) short s16x8;   // 8 bf16 (MFMA A/B frag)
typedef __attribute__((ext_vector_type(4))) float f32x4;   // MFMA C/D frag
typedef __attribute__((ext_vector_type(4))) int   i32x4;

#define BATCH   64
#define SEQ     256
#define HID     1024
#define GATES   4096
#define NWG     256
#define THREADS 256
#define UNITS   8
#define NCOLS   32
#define ROWSTRIDE 2056       // 2048 K + 8 pad elems
#define BH      (BATCH * HID)

// ---- ws layout: flags first (4 KB), h storage after ----
// HIST path: h0[t]/h1[t] each get a UNIQUE slot (write-once addresses -> plain
// cached reads can never be stale; no fences, no ring-protect; L0 free-runs).
// RING fallback (ws too small): 8/2-slot rings with sc0 sc1 bypass reads.
#define HBASE_OFF  4096ull
#define WS_NEED    (HBASE_OFF + 2ull * SEQ * BH * 2)   // 67,112,960 B
#define H0_RS 8
#define H1_RS 2

#define OUT_HN  ((size_t)BATCH * SEQ * HID)
#define OUT_CN  (OUT_HN + 2ull * BATCH * HID)

__device__ __forceinline__ short f2bf(float f) {   // rne fp32->bf16
    unsigned int u = __builtin_bit_cast(unsigned int, f);
    u = (u + 0x7fffu + ((u >> 16) & 1u)) >> 16;
    return (short)u;
}

// ---- monolithic h GEMM over K=1024 (single base + immediate offsets,
// counted-vmcnt pipeline, sched_barrier rule #18) ----
#define GLD(i, OFF, CF) asm volatile("global_load_dwordx4 %0, %1, off offset:" OFF " " CF \
                                     : "=v"(h[i]) : "v"(xrow));
#define MM8(B0) \
    _Pragma("unroll") \
    for (int kk = (B0); kk < (B0) + 8; ++kk) { \
        s16x8 b0 = *(const s16x8*)(s0 + kk * 32); \
        s16x8 b1 = *(const s16x8*)(s1 + kk * 32); \
        s16x8 av = __builtin_bit_cast(s16x8, h[kk]); \
        a0 = __builtin_amdgcn_mfma_f32_16x16x32_bf16(av, b0, a0, 0, 0, 0); \
        a1 = __builtin_amdgcn_mfma_f32_16x16x32_bf16(av, b1, a1, 0, 0, 0); \
    }
#define GEMM_FN(NAME, CF) \
__device__ __forceinline__ void NAME(const bf16* xrow, const bf16* s0, const bf16* s1, \
                                     f32x4& a0, f32x4& a1) \
{ \
    i32x4 h[32]; \
    GLD(0,"0",CF)    GLD(1,"64",CF)   GLD(2,"128",CF)  GLD(3,"192",CF) \
    GLD(4,"256",CF)  GLD(5,"320",CF)  GLD(6,"384",CF)  GLD(7,"448",CF) \
    GLD(8,"512",CF)  GLD(9,"576",CF)  GLD(10,"640",CF) GLD(11,"704",CF) \
    GLD(12,"768",CF) GLD(13,"832",CF) GLD(14,"896",CF) GLD(15,"960",CF) \
    GLD(16,"1024",CF) GLD(17,"1088",CF) GLD(18,"1152",CF) GLD(19,"1216",CF) \
    GLD(20,"1280",CF) GLD(21,"1344",CF) GLD(22,"1408",CF) GLD(23,"1472",CF) \
    asm volatile("s_waitcnt vmcnt(16)"); __builtin_amdgcn_sched_barrier(0); \
    MM8(0) \
    GLD(24,"1536",CF) GLD(25,"1600",CF) GLD(26,"1664",CF) GLD(27,"1728",CF) \
    GLD(28,"1792",CF) GLD(29,"1856",CF) GLD(30,"1920",CF) GLD(31,"1984",CF) \
    asm volatile("s_waitcnt vmcnt(16)"); __builtin_amdgcn_sched_barrier(0); \
    MM8(8) \
    asm volatile("s_waitcnt vmcnt(8)");  __builtin_amdgcn_sched_barrier(0); \
    MM8(16) \
    asm volatile("s_waitcnt vmcnt(0)");  __builtin_amdgcn_sched_barrier(0); \
    MM8(24) \
}
GEMM_FN(gemm_bt, "sc0 sc1")
GEMM_FN(gemm_p,  "")

// Embedding x-GEMM: plain cached fp32 loads.
__device__ __forceinline__ void gemm_f32c(const float* xrow, const bf16* s0, const bf16* s1,
                                          f32x4& a0, f32x4& a1)
{
#pragma unroll
    for (int c = 0; c < 4; ++c) {
        f32x4 xv[16];
#pragma unroll
        for (int i = 0; i < 8; ++i) {
            const float* p = xrow + (c * 8 + i) * 32;
            xv[2 * i]     = *(const f32x4*)p;
            xv[2 * i + 1] = *(const f32x4*)(p + 4);
        }
#pragma unroll
        for (int i = 0; i < 8; ++i) {
            const int kk = c * 8 + i;
            s16x8 af;
#pragma unroll
            for (int j = 0; j < 4; ++j) {
                af[j]     = f2bf(xv[2 * i][j]);
                af[4 + j] = f2bf(xv[2 * i + 1][j]);
            }
            s16x8 b0 = *(const s16x8*)(s0 + kk * 32);
            s16x8 b1 = *(const s16x8*)(s1 + kk * 32);
            a0 = __builtin_amdgcn_mfma_f32_16x16x32_bf16(af, b0, a0, 0, 0, 0);
            a1 = __builtin_amdgcn_mfma_f32_16x16x32_bf16(af, b1, a1, 0, 0, 0);
        }
    }
}

// Per-wave blocking poll of one 128-word flag chain with observed-min caching.
__device__ __forceinline__ void wave_poll(unsigned int* f, int tgt, int* seen) {
    if (tgt <= 0 || *seen >= tgt) return;
    const int l = threadIdx.x & 63;
    unsigned int* p0 = f + l;
    unsigned int* p1 = f + 64 + l;
    int a, b;
    for (;;) {
        a = (int)__hip_atomic_load(p0, __ATOMIC_RELAXED, __HIP_MEMORY_SCOPE_AGENT);
        b = (int)__hip_atomic_load(p1, __ATOMIC_RELAXED, __HIP_MEMORY_SCOPE_AGENT);
        if (__all((a >= tgt) && (b >= tgt))) break;
        __builtin_amdgcn_s_sleep(1);
    }
    int v = (a < b) ? a : b;
#pragma unroll
    for (int off = 32; off; off >>= 1) {
        int w = __shfl_xor(v, off, 64);
        v = (w < v) ? w : v;
    }
    *seen = v;
    asm volatile("" ::: "memory");
}

__global__ void ws_init(unsigned int* p, int n) {
    for (int i = blockIdx.x * blockDim.x + threadIdx.x; i < n; i += gridDim.x * blockDim.x)
        p[i] = 0u;
}

__global__ void __launch_bounds__(THREADS, 1)
lstm_enc(const int* __restrict__ src, const float* __restrict__ Wemb,
         const float* __restrict__ Wih, const float* __restrict__ Whh,
         const float* __restrict__ bih, const float* __restrict__ bhh,
         float* __restrict__ out, bf16* __restrict__ hbuf, int hist_on)
{
    __shared__ __align__(16) bf16 slab[NCOLS][ROWSTRIDE];   // 131,584 B
    __shared__ float bias[NCOLS];

    const int wg    = blockIdx.x;
    const int layer = wg >> 7;
    const int wgl   = wg & 127;
    const int j0    = wgl * UNITS;
    const int tid   = threadIdx.x;
    const int lane  = tid & 63;
    const int wave  = tid >> 6;
    const int m     = lane & 15;
    const int q     = lane >> 4;
    const int kq    = q * 8;
    const int b_a   = wave * 16 + m;           // batch row this lane loads for A

    // ---- weight slab: rows = [i8|f8|g8|o8], K = [W_ih row | W_hh row] ----
    for (int r = 0; r < NCOLS; ++r) {
        int g = r >> 3, u = r & 7;
        size_t grow = (size_t)layer * GATES * HID + (size_t)(g * HID + j0 + u) * HID;
        int k = tid * 8;
        const float* s = (k < HID) ? (Wih + grow + k) : (Whh + grow + (k - HID));
        s16x8 v;
#pragma unroll
        for (int j = 0; j < 8; ++j) v[j] = f2bf(s[j]);
        *(s16x8*)&slab[r][k] = v;
    }
    if (tid < NCOLS) {
        int g = tid >> 3, u = tid & 7;
        int off = layer * GATES + g * HID + j0 + u;
        bias[tid] = bih[off] + bhh[off];
    }
    __syncthreads();                           // slab/bias ready (only barrier)

    unsigned int* flags = (unsigned int*)hbuf;                 // 2 x 512 words
    bf16* hb = (bf16*)((char*)hbuf + HBASE_OFF);
    bf16* h0 = hb;                             // HIST: [256][B][H]; RING: [8][B][H]
    bf16* h1 = hist_on ? hb + (size_t)SEQ * BH : hb + (size_t)H0_RS * BH;
    unsigned int* f0 = flags + wave * 128;             // this wave's L0 chain
    unsigned int* f1 = flags + 512 + wave * 128;       // this wave's L1 chain
    unsigned int* myflag = flags + layer * 512 + wave * 128 + wgl;

    const int u = m & 7;
    const float b_i = bias[u], b_f = bias[8 + u], b_g = bias[16 + u], b_o = bias[24 + u];
    float c_s[4] = {0.f, 0.f, 0.f, 0.f};
    int seenA = 0, seenB = 0;

    int sv = (layer == 0) ? src[b_a * SEQ] : 0;

    // ---- L0 HIST: emb GEMM pipelined ONE STEP AHEAD. eacc holds the emb
    // contribution for the NEXT iteration; computed strictly AFTER the flag
    // post so it overlaps the convoy wait instead of stretching L0's cycle.
    // Per-step accumulation order is unchanged (emb into zeroed acc, then
    // h-GEMM on top) -> bitwise-identical output.
    f32x4 eacc0 = {0.f, 0.f, 0.f, 0.f};
    f32x4 eacc1 = {0.f, 0.f, 0.f, 0.f};
    if (layer == 0 && hist_on) {
        const float* xF = Wemb + (size_t)sv * HID + kq;
        gemm_f32c(xF, &slab[m][kq], &slab[16 + m][kq], eacc0, eacc1);
        sv = src[b_a * SEQ + 1];               // token for t=1 (SEQ >= 2)
    }

    for (int t = 0; t < SEQ; ++t) {
        f32x4 acc0 = {0.f, 0.f, 0.f, 0.f};
        f32x4 acc1 = {0.f, 0.f, 0.f, 0.f};

        if (layer == 0) {
            if (hist_on) {
                acc0 = eacc0;                  // emb[t] was precomputed post-flag
                acc1 = eacc1;
                wave_poll(f0, t, &seenA);      // own chain: h0[t-1] rows ready
                if (t >= 1)
                    gemm_p(h0 + (size_t)(t - 1) * BH + b_a * HID + kq,
                           &slab[m][HID + kq], &slab[16 + m][HID + kq], acc0, acc1);
            } else {
                const float* xF = Wemb + (size_t)sv * HID + kq;
                if (t + 1 < SEQ) sv = src[b_a * SEQ + t + 1];
                gemm_f32c(xF, &slab[m][kq], &slab[16 + m][kq], acc0, acc1);
                wave_poll(f0, t, &seenA);
                if (t >= 1)
                    gemm_bt(h0 + (size_t)((t - 1) & (H0_RS - 1)) * BH + b_a * HID + kq,
                            &slab[m][HID + kq], &slab[16 + m][HID + kq], acc0, acc1);
                wave_poll(f1, t - 7, &seenB);  // ring protect only on reuse
            }
        } else {
            wave_poll(f0, t + 1, &seenA);      // L0 ahead -> mostly cached/skipped
            if (hist_on) {
                gemm_p(h0 + (size_t)t * BH + b_a * HID + kq,
                       &slab[m][kq], &slab[16 + m][kq], acc0, acc1);
                wave_poll(f1, t, &seenB);      // own recurrence (the critical wait)
                if (t >= 1)
                    gemm_p(h1 + (size_t)(t - 1) * BH + b_a * HID + kq,
                           &slab[m][HID + kq], &slab[16 + m][HID + kq], acc0, acc1);
            } else {
                gemm_bt(h0 + (size_t)(t & (H0_RS - 1)) * BH + b_a * HID + kq,
                        &slab[m][kq], &slab[16 + m][kq], acc0, acc1);
                wave_poll(f1, t, &seenB);
                if (t >= 1)
                    gemm_bt(h1 + (size_t)((t - 1) & (H1_RS - 1)) * BH + b_a * HID + kq,
                            &slab[m][HID + kq], &slab[16 + m][HID + kq], acc0, acc1);
            }
        }

        // in-wave epilogue: gate pairs sit in lane pair (u, u+8); same f32 math
        float hval[4];
#pragma unroll
        for (int r = 0; r < 4; ++r) {
            float p0 = __shfl_xor(acc0[r], 8, 64);
            float p1 = __shfl_xor(acc1[r], 8, 64);
            const bool lo = (m < 8);
            float gi = (lo ? acc0[r] : p0) + b_i;
            float gf = (lo ? p0 : acc0[r]) + b_f;
            float gg = (lo ? acc1[r] : p1) + b_g;
            float go = (lo ? p1 : acc1[r]) + b_o;
            float si = 1.f / (1.f + __expf(-gi));
            float sf = 1.f / (1.f + __expf(-gf));
            float so = 1.f / (1.f + __expf(-go));
            c_s[r] = sf * c_s[r] + si * tanhf(gg);
            hval[r] = so * tanhf(c_s[r]);
        }

        // h store (lanes m<8 own the unique copy), write-through to MALL.
        // HIST: slot t is a FRESH address (written exactly once, ever).
        bf16* hw = (layer == 0)
            ? h0 + (size_t)(hist_on ? t : (t & (H0_RS - 1))) * BH
            : h1 + (size_t)(hist_on ? t : (t & (H1_RS - 1))) * BH;
        if (m < 8) {
#pragma unroll
            for (int r = 0; r < 4; ++r) {
                int R = wave * 16 + q * 4 + r;
                __hip_atomic_store((unsigned short*)(hw + (size_t)R * HID + j0 + u),
                                   (unsigned short)f2bf(hval[r]),
                                   __ATOMIC_RELAXED, __HIP_MEMORY_SCOPE_AGENT);
            }
        }
        // per-wave drain + private flag post: no barrier, waves fully decoupled
        asm volatile("s_waitcnt vmcnt(0)"); __builtin_amdgcn_sched_barrier(0);
        asm volatile("" ::: "memory");
        if (lane == 0)
            __hip_atomic_store(myflag, (unsigned int)(t + 1),
                               __ATOMIC_RELAXED, __HIP_MEMORY_SCOPE_AGENT);

        // ---- post-flag work: off the recurrence critical path ----
        if (layer == 0 && hist_on && t + 1 < SEQ) {
            // emb GEMM for step t+1 overlaps the convoy wait
            const float* xF = Wemb + (size_t)sv * HID + kq;
            if (t + 2 < SEQ) sv = src[b_a * SEQ + t + 2];
            eacc0 = (f32x4){0.f, 0.f, 0.f, 0.f};
            eacc1 = (f32x4){0.f, 0.f, 0.f, 0.f};
            gemm_f32c(xF, &slab[m][kq], &slab[16 + m][kq], eacc0, eacc1);
        }
        if (layer == 1 && m < 8) {
#pragma unroll
            for (int r = 0; r < 4; ++r) {
                int R = wave * 16 + q * 4 + r;
                out[((size_t)R * SEQ + t) * HID + j0 + u] = hval[r];
            }
        }
        if (t == SEQ - 1 && m < 8) {
#pragma unroll
            for (int r = 0; r < 4; ++r) {
                int R = wave * 16 + q * 4 + r;
                size_t o = ((size_t)layer * BATCH + R) * HID + j0 + u;
                out[OUT_HN + o] = hval[r];
                out[OUT_CN + o] = c_s[r];
            }
        }
    }
}

extern "C" void kernel_launch(void* const* d_in, const int* in_sizes, int n_in,
                              void* d_out, int out_size, void* d_ws, size_t ws_size,
                              hipStream_t stream) {
    const int*   src  = (const int*)d_in[0];
    const float* emb  = (const float*)d_in[1];
    const float* W_ih = (const float*)d_in[2];
    const float* W_hh = (const float*)d_in[3];
    const float* b_ih = (const float*)d_in[4];
    const float* b_hh = (const float*)d_in[5];
    float* out  = (float*)d_out;
    bf16*  hbuf = (bf16*)d_ws;

    // zero the 1024 flag words at ws base (ws re-poisoned 0xAA each replay;
    // h slots need no init: each is written before it is ever read)
    ws_init<<<4, 256, 0, stream>>>((unsigned int*)d_ws, 1024);

    int hist_on = (ws_size >= (size_t)WS_NEED) ? 1 : 0;

    void* args[] = {&src, &emb, &W_ih, &W_hh, &b_ih, &b_hh, &out, &hbuf, &hist_on};
    hipLaunchCooperativeKernel((void*)lstm_enc, dim3(NWG), dim3(THREADS),
                               args, 0, stream);
}